// Round 13
// baseline (338.056 us; speedup 1.0000x reference)
//
#include <hip/hip_runtime.h>
#include <hip/hip_bf16.h>
#include <math.h>

#define N_NODES 200000
#define EMB_DIM 64
#define E_ADJ 1600000
#define E_TR 65536
#define NUM_NEG 16
#define EPS 1e-7f
#define MIN_NORM 1e-15f
#define MAX_SQDIST 50.0f
#define MARGIN 0.1f
#define LOSS_BLOCKS (E_TR / 4)     // 16384 blocks, 4 edges (waves) each
#define SPMM_BLOCKS 2048           // persistent: 8 blocks/CU x 256 CU
#define NWAVES (SPMM_BLOCKS * 4)   // 8192 waves
#define RPW 25                     // rows per wave (contiguous block)
#define LDS_CAP 512                // staged edges per wave (~200 expected)

#define PACK_BLOCKS ((E_ADJ + 255) / 256)        // 6250
#define RP_BLOCKS   ((N_NODES + 1 + 255) / 256)  // 782
#define LOG_BLOCKS  ((N_NODES + 15) / 16)        // 12500

typedef float f4 __attribute__((ext_vector_type(4)));

__device__ __forceinline__ float group_reduce16(float v) {
    v += __shfl_xor(v, 8, 64);
    v += __shfl_xor(v, 4, 64);
    v += __shfl_xor(v, 2, 64);
    v += __shfl_xor(v, 1, 64);
    return v;
}

__device__ __forceinline__ float dot4(f4 a, f4 b) {
    return a.x * b.x + a.y * b.y + a.z * b.z + a.w * b.w;
}

// ---- bf16 pack/unpack (RNE, unbiased) ----
__device__ __forceinline__ unsigned bfr(float f) {
    unsigned u = __float_as_uint(f);
    return (u + 0x7fffu + ((u >> 16) & 1u)) >> 16;
}
__device__ __forceinline__ uint2 f42bf(f4 v) {
    return make_uint2(bfr(v.x) | (bfr(v.y) << 16), bfr(v.z) | (bfr(v.w) << 16));
}
__device__ __forceinline__ f4 bf2f4(uint2 g) {
    f4 r;
    r.x = __uint_as_float(g.x << 16);
    r.y = __uint_as_float(g.x & 0xffff0000u);
    r.z = __uint_as_float(g.y << 16);
    r.w = __uint_as_float(g.y & 0xffff0000u);
    return r;
}

// Prelude: pack edges + row_ptr + logmap0, one dispatch (block-range split).
__global__ void prelude_kernel(const int* __restrict__ cols, const float* __restrict__ vals,
                               int2* __restrict__ ev, const int* __restrict__ rows,
                               int* __restrict__ rp, const float* __restrict__ w,
                               uint2* __restrict__ xt) {
    int b = blockIdx.x;
    if (b < PACK_BLOCKS) {
        int i = b * 256 + threadIdx.x;
        if (i < E_ADJ) ev[i] = make_int2(cols[i] << 4, __float_as_int(vals[i]));
    } else if (b < PACK_BLOCKS + RP_BLOCKS) {
        int r = (b - PACK_BLOCKS) * 256 + threadIdx.x;
        if (r <= N_NODES) {
            int lo = 0, hi = E_ADJ;
            while (lo < hi) {
                int mid = (lo + hi) >> 1;
                if (rows[mid] < r) lo = mid + 1; else hi = mid;
            }
            rp[r] = lo;
        }
    } else {
        int bb = b - PACK_BLOCKS - RP_BLOCKS;
        int wave = bb * 4 + (threadIdx.x >> 6);
        int lane = threadIdx.x & 63;
        int e = lane >> 4, d = lane & 15;
        int node = wave * 4 + e;
        if (node < N_NODES) {
            f4 v = ((const f4*)w)[(node << 4) + d];
            f4 y = v;
            if (d == 0) y.x = 0.0f;
            float n2 = group_reduce16(dot4(y, y));
            float ynorm = fmaxf(sqrtf(n2), MIN_NORM);
            float w0 = __shfl(v.x, lane & 48, 64);
            float theta = fmaxf(w0, 1.0f + EPS);
            float scale = acoshf(theta) / ynorm;
            xt[(node << 4) + d] = f42bf(y * scale);
        }
    }
}

// Per-group (16-lane) row accumulate: strict edge-index order, unroll x2.
// Group owns the whole 64-dim row (16 lanes x f4). No cross-group reduce.
__device__ __forceinline__ f4 row_accum(const uint2* __restrict__ h_in,
                                        const int2* __restrict__ ev,
                                        const int2* L, int ebase, int staged,
                                        int s, int e, int d) {
    f4 acc = {0.f, 0.f, 0.f, 0.f};
    int k = s;
    for (; k + 2 <= e; k += 2) {
        int o0 = k - ebase;
        int2 cv0, cv1;
        if (o0 + 1 < staged) { cv0 = L[o0]; cv1 = L[o0 + 1]; }
        else                 { cv0 = ev[k]; cv1 = ev[k + 1]; }
        uint2 g0 = h_in[cv0.x + d];
        uint2 g1 = h_in[cv1.x + d];
        acc += bf2f4(g0) * __int_as_float(cv0.y);
        acc += bf2f4(g1) * __int_as_float(cv1.y);
    }
    if (k < e) {
        int o = k - ebase;
        int2 cv;
        if (o < staged) cv = L[o]; else cv = ev[k];
        uint2 gg = h_in[cv.x + d];
        acc += bf2f4(gg) * __int_as_float(cv.y);
    }
    return acc;
}

// Kernel: persistent SpMM layer. Wave owns RPW contiguous rows; each 16-lane
// group processes one row independently (4 rows in flight, no per-row stall).
__global__ __launch_bounds__(256) void spmm_kernel(const uint2* __restrict__ h_in,
                                                   uint2* __restrict__ h_out,
                                                   const int2* __restrict__ ev,
                                                   const int* __restrict__ rp) {
    __shared__ int2 evs[4][LDS_CAP];               // 16 KB/block
    int wib = threadIdx.x >> 6;
    int lane = threadIdx.x & 63;
    int g = lane >> 4, d = lane & 15;
    int wid = __builtin_amdgcn_readfirstlane(blockIdx.x * 4 + wib);
    int r0 = wid * RPW;
    if (r0 >= N_NODES) return;                     // whole block exits together
    int r1 = min(r0 + RPW, N_NODES);
    int ebase = rp[r0];                            // s_load
    int etot  = rp[r1];
    int staged = min(etot - ebase, LDS_CAP);
    int2* L = evs[wib];
    for (int k = lane; k < staged; k += 64)        // coalesced bulk stage
        L[k] = ev[ebase + k];
    __syncthreads();

    for (int base = r0; base < r1; base += 4) {
        int row = base + g;
        bool valid = row < r1;
        int s = 0, e = 0;
        if (valid) { s = rp[row]; e = rp[row + 1]; }   // group-uniform vector loads
        f4 acc = row_accum(h_in, ev, L, ebase, staged, s, e, d);
        if (valid)
            h_out[(row << 4) + d] = f42bf(acc);    // 4 rows contiguous/wave
    }
}

// Kernel: persistent fused layer-3 SpMM + (h1+h2+h3) + expmap0 + proj.
// Emits fp32 h (all score math) + a SHIFTED bf16 mirror (first component - 1)
// used ONLY for hard-neg mining: removes the ~1.0-scale cancellation that made
// plain-bf16 mining noise swamp the d2 ranking (R11/R12 failures).
__global__ __launch_bounds__(256) void spmm_expmap_kernel(const uint2* __restrict__ h_gather,
                                                          const uint2* __restrict__ h1,
                                                          const uint2* __restrict__ h2,
                                                          float* __restrict__ h,
                                                          uint2* __restrict__ hm,
                                                          const int2* __restrict__ ev,
                                                          const int* __restrict__ rp) {
    __shared__ int2 evs[4][LDS_CAP];
    int wib = threadIdx.x >> 6;
    int lane = threadIdx.x & 63;
    int g = lane >> 4, d = lane & 15;
    int wid = __builtin_amdgcn_readfirstlane(blockIdx.x * 4 + wib);
    int r0 = wid * RPW;
    if (r0 >= N_NODES) return;
    int r1 = min(r0 + RPW, N_NODES);
    int ebase = rp[r0];
    int etot  = rp[r1];
    int staged = min(etot - ebase, LDS_CAP);
    int2* L = evs[wib];
    for (int k = lane; k < staged; k += 64)
        L[k] = ev[ebase + k];
    __syncthreads();

    for (int base = r0; base < r1; base += 4) {
        int row = base + g;
        bool valid = row < r1;
        int s = 0, e = 0;
        int oi = (row << 4) + d;
        f4 a1 = {0.f,0.f,0.f,0.f}, a2 = {0.f,0.f,0.f,0.f};
        if (valid) {
            s = rp[row]; e = rp[row + 1];
            a1 = bf2f4(h1[oi]);                    // issue early, overlap gathers
            a2 = bf2f4(h2[oi]);
        }
        f4 acc = row_accum(h_gather, ev, L, ebase, staged, s, e, d);
        if (valid) {
            f4 u = (a1 + a2) + acc;                // match ref accumulate order
            f4 x = u;
            if (d == 0) x.x = 0.0f;
            float n2 = group_reduce16(dot4(x, x)); // group-local: whole row in group
            float xn = fmaxf(sqrtf(n2), MIN_NORM);
            float sh = sinhf(xn);
            f4 rest = x * (sh / xn);
            float r2 = group_reduce16(dot4(rest, rest));
            float first = sqrtf(1.0f + r2);
            f4 ov = rest;
            if (d == 0) ov.x = first;
            ((f4*)h)[oi] = ov;                     // fp32 h for all score math
            f4 mv = ov;
            if (d == 0) mv.x = first - 1.0f;       // shift removes 1.0-scale quantization
            hm[oi] = f42bf(mv);                    // bf16 mirror for mining only
        }
    }
}

// Kernel: triplet loss + hard-negative mining. One wave per edge; lane=16e+d.
// Mining: direct-difference d2 on the shifted bf16 mirror (1 line/neg, no
// cancellation) -> top-2; fp32 re-rank with the reference's exact direct d2.
__global__ void loss_kernel(const float* __restrict__ h, const uint2* __restrict__ hm,
                            const int* __restrict__ anchor, const int* __restrict__ pos,
                            const int* __restrict__ neg, float* __restrict__ partials) {
    int wib = threadIdx.x >> 6;
    int lane = threadIdx.x & 63;
    int e = lane >> 4, d = lane & 15;
    int i = __builtin_amdgcn_readfirstlane(blockIdx.x * 4 + wib);
    const f4* H = (const f4*)h;

    int ia = anchor[i], ip = pos[i];               // s_load
    f4 a4 = H[(ia << 4) + d];
    f4 p4 = H[(ip << 4) + d];
    f4 p4m = p4;
    if (d == 0) p4m.x = p4.x - 1.0f;               // exact (Sterbenz, p0 in [1,2))
    int4 nb4 = ((const int4*)(neg + (size_t)i * NUM_NEG))[e];  // group e: j = 4e+b

    float s[4];
    {
        f4 df;
        df = bf2f4(hm[(nb4.x << 4) + d]) - p4m; s[0] = dot4(df, df);
        df = bf2f4(hm[(nb4.y << 4) + d]) - p4m; s[1] = dot4(df, df);
        df = bf2f4(hm[(nb4.z << 4) + d]) - p4m; s[2] = dot4(df, df);
        df = bf2f4(hm[(nb4.w << 4) + d]) - p4m; s[3] = dot4(df, df);
    }
    float dap = dot4(a4, p4);

    // reduce-scatter the 4 partial-d2 values across the 16-lane group
    {
        bool hi = (d & 8) != 0;
        float send0 = hi ? s[0] : s[2];
        float send1 = hi ? s[1] : s[3];
        float r0 = __shfl_xor(send0, 8, 64);
        float r1 = __shfl_xor(send1, 8, 64);
        float k0 = hi ? s[2] : s[0];
        float k1 = hi ? s[3] : s[1];
        s[0] = k0 + r0;
        s[1] = k1 + r1;
    }
    float sv;
    {
        bool hi = (d & 4) != 0;
        float send = hi ? s[0] : s[1];
        float r = __shfl_xor(send, 4, 64);
        float k = hi ? s[1] : s[0];
        sv = k + r;
    }
    sv += __shfl_xor(sv, 2, 64);
    sv += __shfl_xor(sv, 1, 64);
    // lane (e,d) holds d2 for j = 4e + b, b = ((d>>3)&1)*2 + ((d>>2)&1)
    int b_lane = ((d >> 3) & 1) * 2 + ((d >> 2) & 1);
    int j_lane = 4 * e + b_lane;

    float d2l = sv;                                // mining d2 (bf16-input, low noise)
    // top-1 argmin (first-occurrence tie-break)
    float m1 = d2l; int j1 = j_lane;
    #pragma unroll
    for (int off = 32; off > 0; off >>= 1) {
        float od = __shfl_xor(m1, off, 64);
        int   oj = __shfl_xor(j1, off, 64);
        if (od < m1 || (od == m1 && oj < j1)) { m1 = od; j1 = oj; }
    }
    // top-2: mask out j1, argmin again
    float m2 = (j_lane == j1) ? 3.4e38f : d2l; int j2 = j_lane;
    #pragma unroll
    for (int off = 32; off > 0; off >>= 1) {
        float od = __shfl_xor(m2, off, 64);
        int   oj = __shfl_xor(j2, off, 64);
        if (od < m2 || (od == m2 && oj < j2)) { m2 = od; j2 = oj; }
    }
    // fp32 re-rank of the two candidates: direct d2 = sum((n-p)^2), ref formula
    int n1 = neg[(size_t)i * NUM_NEG + __builtin_amdgcn_readfirstlane(j1)];  // s_load
    int n2 = neg[(size_t)i * NUM_NEG + __builtin_amdgcn_readfirstlane(j2)];
    f4 w1 = H[(n1 << 4) + d];
    f4 w2 = H[(n2 << 4) + d];
    f4 df1 = w1 - p4;
    f4 df2 = w2 - p4;
    float d2f1 = group_reduce16(dot4(df1, df1));
    float d2f2 = group_reduce16(dot4(df2, df2));
    bool take2 = (d2f2 < d2f1) || (d2f2 == d2f1 && j2 < j1);   // wave-uniform
    f4 w4;
    w4.x = take2 ? w2.x : w1.x; w4.y = take2 ? w2.y : w1.y;
    w4.z = take2 ? w2.z : w1.z; w4.w = take2 ? w2.w : w1.w;
    float dan = group_reduce16(dot4(a4, w4));
    dap = group_reduce16(dap);

    float loss = 0.0f;
    if (lane == 0) {
        float a0 = a4.x, p0 = p4.x, n0 = w4.x;
        float mink = dap - 2.0f * a0 * p0;
        float th = fmaxf(-mink, 1.0f + EPS);
        float ac = acoshf(th);
        float pos_score = fminf(ac * ac, MAX_SQDIST);
        float score = (1.0f - mink - a0 - p0) / (a0 * p0);
        float wgt = 1.0f / (1.0f + expf(score));        // sigmoid(-score)
        float minkn = dan - 2.0f * a0 * n0;
        float thn = fmaxf(-minkn, 1.0f + EPS);
        float acn = acoshf(thn);
        float neg_score = fminf(acn * acn, MAX_SQDIST);
        loss = fmaxf(pos_score - neg_score + MARGIN * wgt, 0.0f);
    }
    __shared__ float part[4];
    if (lane == 0) part[wib] = loss;
    __syncthreads();
    if (threadIdx.x == 0)
        partials[blockIdx.x] = part[0] + part[1] + part[2] + part[3];
}

// Final reduce. Single block, 1024 threads.
__global__ void reduce_kernel(const float* __restrict__ partials, float* __restrict__ out) {
    int tid = threadIdx.x;
    float s = 0.0f;
    for (int i = tid; i < LOSS_BLOCKS; i += 1024)
        s += partials[i];
    #pragma unroll
    for (int off = 32; off > 0; off >>= 1)
        s += __shfl_xor(s, off, 64);
    __shared__ float part[16];
    if ((tid & 63) == 0) part[tid >> 6] = s;
    __syncthreads();
    if (tid == 0) {
        float t = 0.0f;
        #pragma unroll
        for (int k = 0; k < 16; ++k) t += part[k];
        out[0] = t;
    }
}

extern "C" void kernel_launch(void* const* d_in, const int* in_sizes, int n_in,
                              void* d_out, int out_size, void* d_ws, size_t ws_size,
                              hipStream_t stream) {
    const float* weight   = (const float*)d_in[0];
    const float* adj_vals = (const float*)d_in[1];
    const int*   adj_row  = (const int*)d_in[2];
    const int*   adj_col  = (const int*)d_in[3];
    const int*   anchor   = (const int*)d_in[4];
    const int*   pos      = (const int*)d_in[5];
    const int*   neg      = (const int*)d_in[6];
    float* out = (float*)d_out;

    const size_t NODEF32 = (size_t)N_NODES * EMB_DIM * sizeof(float);           // 51.2 MB
    const size_t NODEBF  = (size_t)N_NODES * EMB_DIM * sizeof(unsigned short);  // 25.6 MB
    const size_t MB = 1024 * 1024;
    char* ws = (char*)d_ws;
    float* hfin = (float*)(ws);                            // final h fp32 (51.2 MB)
    uint2* bf0  = (uint2*)(ws + NODEF32);                  // x_t bf16
    uint2* bf1  = (uint2*)(ws + NODEF32 + NODEBF);         // h1 bf16
    uint2* bf2  = (uint2*)(ws + NODEF32 + 2 * NODEBF);     // h2 bf16
    uint2* hm   = (uint2*)(ws + NODEF32 + 3 * NODEBF);     // shifted bf16 mirror
    int*   rp   = (int*)  (ws + NODEF32 + 4 * NODEBF);                // row_ptr (800 KB)
    int2*  ev   = (int2*) (ws + NODEF32 + 4 * NODEBF + 2 * MB);       // packed edges (12.8 MB)
    float* partials = (float*)(ws + NODEF32 + 4 * NODEBF + 16 * MB);  // 64 KB

    prelude_kernel<<<PACK_BLOCKS + RP_BLOCKS + LOG_BLOCKS, 256, 0, stream>>>(
        adj_col, adj_vals, ev, adj_row, rp, weight, bf0);
    spmm_kernel<<<SPMM_BLOCKS, 256, 0, stream>>>(bf0, bf1, ev, rp);
    spmm_kernel<<<SPMM_BLOCKS, 256, 0, stream>>>(bf1, bf2, ev, rp);
    spmm_expmap_kernel<<<SPMM_BLOCKS, 256, 0, stream>>>(bf2, bf1, bf2, hfin, hm, ev, rp);
    loss_kernel<<<LOSS_BLOCKS, 256, 0, stream>>>(hfin, hm, anchor, pos, neg, partials);
    reduce_kernel<<<1, 1024, 0, stream>>>(partials, out);
}